// Round 9
// baseline (129.326 us; speedup 1.0000x reference)
//
#include <hip/hip_runtime.h>
#include <hip/hip_bf16.h>

using bf16 = __hip_bfloat16;
typedef short bf16x8 __attribute__((ext_vector_type(8)));
typedef float f32x4 __attribute__((ext_vector_type(4)));

#define DD 256
#define MTOT 65536   // B*QH*QW = 16*64*64

static __device__ __forceinline__ short f2bs(float f) {
    bf16 h = __float2bfloat16(f);          // RNE
    return *reinterpret_cast<short*>(&h);
}
static __device__ __forceinline__ float bs2f(short s) {
    unsigned u = (unsigned)(unsigned short)s << 16;
    return __uint_as_float(u);
}

// async global->LDS, 16B per lane; LDS dest = wave-uniform base + lane*16
static __device__ __forceinline__ void gll16(const void* g, void* l) {
    __builtin_amdgcn_global_load_lds(
        (const __attribute__((address_space(1))) unsigned int*)g,
        (__attribute__((address_space(3))) unsigned int*)l, 16, 0, 0);
}

// Pre-swizzled BT layout in GLOBAL: element (n = out col, k) at flat
//   n*256 + (((k>>3) ^ (n&7)) << 3 | (k&7))
// 16B-granule XOR closed within each 64-k slice -> LDS staging is a linear
// copy, ds_read at [n][lg ^ (n&7)] bank-optimal (R5/R7: 0 conflicts).
static __device__ __forceinline__ int swz_idx(int n, int k) {
    return n * 256 + ((((k >> 3) ^ (n & 7)) << 3) | (k & 7));
}

// ---------------- K0: convert+transpose+swizzle weights (f32 -> bf16) ----------------
__global__ __launch_bounds__(256) void k_transpose(
    const float* __restrict__ Wb, const float* __restrict__ Wk, const float* __restrict__ Wm,
    const float* __restrict__ Woff, const float* __restrict__ WA,
    bf16* __restrict__ WbT, bf16* __restrict__ WkT, bf16* __restrict__ WmT,
    bf16* __restrict__ WoffAT)
{
    int idx = blockIdx.x * 256 + threadIdx.x;
    if (idx < 3 * 65536) {
        int which = idx >> 16, e = idx & 65535;
        int i = e >> 8, j = e & 255;               // in[i][j]: i = k, j = n
        const float* src = which == 0 ? Wb : (which == 1 ? Wk : Wm);
        bf16*        dst = which == 0 ? WbT : (which == 1 ? WkT : WmT);
        dst[swz_idx(j, i)] = __float2bfloat16(src[e]);
    } else {
        int e = idx - 3 * 65536;
        if (e < 96 * 256) {
            int j = e >> 8, i = e & 255;           // out row j = n (0..95), k = i
            WoffAT[swz_idx(j, i)] = __float2bfloat16((j < 64) ? Woff[i * 64 + j]
                                                              : WA[i * 32 + (j - 64)]);
        }
    }
}

// ---------------- double-buffered global_load_lds MFMA mainloop (R7, unchanged) ----------------
template <int NTW, int NCOLS, bool AF32>
static __device__ __forceinline__ void gemm_lds2(
    const void* __restrict__ Av, const bf16* __restrict__ BTswz,
    bf16* __restrict__ Bs, char* __restrict__ As,
    int row0, int tid, f32x4 (&acc)[2][NTW])
{
    const int wave = tid >> 6, lane = tid & 63;
    const int rg = wave >> 1, cg = wave & 1;
    const int rsub = lane & 15, kg = lane >> 4;
    constexpr int SB = NCOLS / 32;
    constexpr int SA = AF32 ? 4 : 2;
    constexpr int ABYTES = AF32 ? 16384 : 8192;

    auto stageB = [&](int s) {
#pragma unroll
        for (int i = 0; i < SB; ++i) {
            int cc = wave * SB + i;
            int i16 = cc * 64 + lane;
            int n = i16 >> 3, lg = i16 & 7;
            gll16(BTswz + (size_t)n * 256 + s * 64 + lg * 8, (char*)Bs + (size_t)i16 * 16);
        }
    };
    auto stageA = [&](int s, int buf) {
#pragma unroll
        for (int i = 0; i < SA; ++i) {
            if constexpr (AF32) {
                int cc = wave * 4 + i;
                int row = cc * 4 + (lane >> 4);
                int g = (lane & 15) ^ (row & 15);
                gll16((const float*)Av + (size_t)(row0 + row) * DD + s * 64 + g * 4,
                      As + (size_t)buf * ABYTES + cc * 1024 + lane * 16);
            } else {
                int cc = wave * 2 + i;
                int row = cc * 8 + (lane >> 3);
                int g = (lane & 7) ^ (row & 7);
                gll16((const bf16*)Av + (size_t)(row0 + row) * DD + s * 64 + g * 8,
                      As + (size_t)buf * ABYTES + cc * 1024 + lane * 16);
            }
        }
    };

    stageA(0, 0);
    int cur = 0;
#pragma unroll
    for (int s = 0; s < 4; ++s) {
        stageB(s);
        if (s < 3) {
            stageA(s + 1, cur ^ 1);
            asm volatile("s_waitcnt vmcnt(%0)" :: "i"(SA) : "memory");
        } else {
            asm volatile("s_waitcnt vmcnt(0)" ::: "memory");
        }
        __builtin_amdgcn_s_barrier();
#pragma unroll
        for (int kkl = 0; kkl < 2; ++kkl) {
            bf16x8 afr[2];
#pragma unroll
            for (int st = 0; st < 2; ++st) {
                int row = rg * 32 + st * 16 + rsub;
                if constexpr (AF32) {
                    const char* base = As + cur * ABYTES + row * 256;
                    int G0 = kkl * 8 + kg * 2;
                    f32x4 v0 = *(const f32x4*)(base + ((G0 ^ (row & 15)) << 4));
                    f32x4 v1 = *(const f32x4*)(base + (((G0 + 1) ^ (row & 15)) << 4));
                    bf16x8 a;
#pragma unroll
                    for (int e = 0; e < 4; ++e) { a[e] = f2bs(v0[e]); a[e + 4] = f2bs(v1[e]); }
                    afr[st] = a;
                } else {
                    const char* base = As + cur * ABYTES + row * 128;
                    int g = kkl * 4 + kg;
                    afr[st] = *(const bf16x8*)(base + ((g ^ (row & 7)) << 4));
                }
            }
            int lg = kkl * 4 + kg;
#pragma unroll
            for (int nt = 0; nt < NTW; ++nt) {
                int n = cg * (NTW * 16) + nt * 16 + rsub;
                bf16x8 b = *(const bf16x8*)((const char*)Bs + (size_t)n * 128 + ((lg ^ (n & 7)) << 4));
                acc[0][nt] = __builtin_amdgcn_mfma_f32_16x16x32_bf16(afr[0], b, acc[0][nt], 0, 0, 0);
                acc[1][nt] = __builtin_amdgcn_mfma_f32_16x16x32_bf16(afr[1], b, acc[1][nt], 0, 0, 0);
            }
        }
        asm volatile("s_waitcnt lgkmcnt(0)" ::: "memory");
        __builtin_amdgcn_s_barrier();
        cur ^= 1;
    }
}

// ---------------- body: fused sq + offA (R8 k_gemm_sqoffA, LDS passed in) ----------------
static __device__ void body_sqoffA(
    int bid, char* smem,
    const float* __restrict__ src, const bf16* __restrict__ WbT, const float* __restrict__ bb,
    const bf16* __restrict__ WoffAT, const float* __restrict__ boff, const float* __restrict__ bA,
    float* __restrict__ off_ws, float* __restrict__ A_ws)
{
    bf16* Bs = (bf16*)smem;            // 32 KB
    char* As = smem + 32768;           // 32 KB
    int tid = threadIdx.x, lane = tid & 63, wave = tid >> 6;
    int row0 = bid * 64;
    f32x4 acc[2][8] = {};
    gemm_lds2<8, 256, true>(src, WbT, Bs, As, row0, tid, acc);

    // phase 2: write sq tile (bias + bf16) into As, swizzled
    {
        int col = lane & 15;
        int jbase = (wave & 1) * 128;
        int lrb = (wave >> 1) * 32 + ((lane >> 4) << 2);
#pragma unroll
        for (int mt = 0; mt < 2; ++mt)
#pragma unroll
            for (int nt = 0; nt < 8; ++nt) {
                int j = jbase + nt * 16 + col;
                float bias = bb[j];
                int g = j >> 3;
#pragma unroll
                for (int r = 0; r < 4; ++r) {
                    int lr = lrb + mt * 16 + r;
                    *(short*)(As + lr * 512 + (((g ^ (lr & 7)) << 4)) + (j & 7) * 2) =
                        f2bs(acc[mt][nt][r] + bias);
                }
            }
    }
    __syncthreads();

    // phase 3: offA mainloop; A full-K resident in As, B sliced (12 KB) dbuf in Bs
    f32x4 acc2[2][3] = {};
    const int rsub = lane & 15, kg = lane >> 4;
    const int rg = wave >> 1, cg2 = wave & 1;
    auto stageOB = [&](int s, int buf) {
#pragma unroll
        for (int i = 0; i < 3; ++i) {
            int i16 = (wave * 3 + i) * 64 + lane;      // 0..767 granules
            int n = i16 >> 3, lg = i16 & 7;
            gll16(WoffAT + (size_t)n * 256 + s * 64 + lg * 8,
                  (char*)Bs + buf * 12288 + (size_t)i16 * 16);
        }
    };
    stageOB(0, 0);
    int cur = 0;
#pragma unroll
    for (int s = 0; s < 4; ++s) {
        if (s < 3) {
            stageOB(s + 1, cur ^ 1);
            asm volatile("s_waitcnt vmcnt(3)" ::: "memory");   // slice s done; s+1 in flight
        } else {
            asm volatile("s_waitcnt vmcnt(0)" ::: "memory");
        }
        __builtin_amdgcn_s_barrier();
#pragma unroll
        for (int kkl = 0; kkl < 2; ++kkl) {
            bf16x8 afr[2];
#pragma unroll
            for (int st = 0; st < 2; ++st) {
                int lr = rg * 32 + st * 16 + rsub;
                int g = s * 8 + kkl * 4 + kg;
                afr[st] = *(const bf16x8*)(As + lr * 512 + ((g ^ (lr & 7)) << 4));
            }
            int lg = kkl * 4 + kg;
#pragma unroll
            for (int nt = 0; nt < 3; ++nt) {
                int n = cg2 * 48 + nt * 16 + rsub;
                bf16x8 b = *(const bf16x8*)((const char*)Bs + cur * 12288 + (size_t)n * 128
                                            + ((lg ^ (n & 7)) << 4));
                acc2[0][nt] = __builtin_amdgcn_mfma_f32_16x16x32_bf16(afr[0], b, acc2[0][nt], 0, 0, 0);
                acc2[1][nt] = __builtin_amdgcn_mfma_f32_16x16x32_bf16(afr[1], b, acc2[1][nt], 0, 0, 0);
            }
        }
        asm volatile("s_waitcnt lgkmcnt(0)" ::: "memory");
        __builtin_amdgcn_s_barrier();
        cur ^= 1;
    }
    // epilogue: off + softmax(A)
    int col = lane & 15;
    int jbase = cg2 * 48;
    int rb = row0 + rg * 32 + ((lane >> 4) << 2);
#pragma unroll
    for (int mt = 0; mt < 2; ++mt) {
#pragma unroll
        for (int nt = 0; nt < 3; ++nt) {
            int j = jbase + nt * 16 + col;          // 0..95
            if (j < 64) {                           // offsets
                float bias = boff[j];
#pragma unroll
                for (int r = 0; r < 4; ++r) {
                    int m = rb + mt * 16 + r;
                    off_ws[(size_t)m * 64 + j] = acc2[mt][nt][r] + bias;
                }
            } else {                                // A logits, ac = j-64 in 0..31
                int ac = j - 64;                    // head = ac>>2, slot = ac&3
                float bias = bA[ac];
#pragma unroll
                for (int r = 0; r < 4; ++r) {
                    int m = rb + mt * 16 + r;
                    float v  = acc2[mt][nt][r] + bias;
                    float mx = fmaxf(v, __shfl_xor(v, 1));
                    mx       = fmaxf(mx, __shfl_xor(mx, 2));
                    float e  = __expf(v - mx);
                    float su = e + __shfl_xor(e, 1);
                    su      += __shfl_xor(su, 2);
                    A_ws[(size_t)m * 32 + ac] = e / su;
                }
            }
        }
    }
}

// ---------------- body: kf = keys @ Wk + bk (R7 k_gemm_kf, LDS passed in) ----------------
static __device__ void body_kf(
    int bid, char* smem,
    const float* __restrict__ keys, const bf16* __restrict__ WkT,
    const float* __restrict__ bk, bf16* __restrict__ kf)
{
    bf16* Bs = (bf16*)smem;            // 32 KB
    char* As = smem + 32768;           // 32 KB (f32 dbuf)
    int tid = threadIdx.x, lane = tid & 63, wave = tid >> 6;
    int row0 = bid * 64;
    f32x4 acc[2][8] = {};
    gemm_lds2<8, 256, true>(keys, WkT, Bs, As, row0, tid, acc);
    int col = lane & 15;
    int jbase = (wave & 1) * 128;
    int rb = row0 + (wave >> 1) * 32 + ((lane >> 4) << 2);
#pragma unroll
    for (int mt = 0; mt < 2; ++mt)
#pragma unroll
        for (int nt = 0; nt < 8; ++nt) {
            int j = jbase + nt * 16 + col;         // head h=j>>5, channel c=j&31
            float bias = bk[j];
#pragma unroll
            for (int r = 0; r < 4; ++r) {
                int m = rb + mt * 16 + r;          // b = m>>12, pix = m&4095
                size_t dst = (((size_t)(m >> 12) * 8 + (j >> 5)) * 4096 + (m & 4095)) * 32 + (j & 31);
                kf[dst] = __float2bfloat16(acc[mt][nt][r] + bias);
            }
        }
}

// ---------------- K1: role-split fused kernel: even blocks sqoffA, odd blocks kf ----------------
__global__ __launch_bounds__(256) void k_fusedA(
    const float* __restrict__ src, const bf16* __restrict__ WbT, const float* __restrict__ bb,
    const bf16* __restrict__ WoffAT, const float* __restrict__ boff, const float* __restrict__ bA,
    float* __restrict__ off_ws, float* __restrict__ A_ws,
    const float* __restrict__ keys, const bf16* __restrict__ WkT,
    const float* __restrict__ bk, bf16* __restrict__ kf)
{
    __shared__ __align__(16) char smem[65536];
    int bid = blockIdx.x;
    if (bid & 1)
        body_kf(bid >> 1, smem, keys, WkT, bk, kf);
    else
        body_sqoffA(bid >> 1, smem, src, WbT, bb, WoffAT, boff, bA, off_ws, A_ws);
}

// ---------------- K2: fused sample + out GEMM ----------------
// Block = 64 queries. Phase S: gather into swizzled LDS feat tile [64][256] bf16.
// Phase G: out = feat @ WmT + bm, A-frags from LDS, B 32KB slices staged per-s.
__global__ __launch_bounds__(256) void k_sample_out(
    const float* __restrict__ ref_point, const float* __restrict__ off_ws,
    const float* __restrict__ A_ws, const bf16* __restrict__ kf,
    const bf16* __restrict__ WmT, const float* __restrict__ bm,
    float* __restrict__ out)
{
    __shared__ __align__(16) char smem[65536];
    bf16* Bs = (bf16*)smem;            // 32 KB B slice
    char* As = smem + 32768;           // 32 KB feat tile, swizzled
    int tid = threadIdx.x;
    int row0 = blockIdx.x * 64;
    int q  = tid >> 5;                 // 0..7
    int h  = (tid >> 2) & 7;           // 0..7
    int cg = tid & 3;                  // channels cg*8..cg*8+7
    int jcol = h * 32 + cg * 8;
    int gcol = jcol >> 3;

#pragma unroll 2
    for (int qq = 0; qq < 8; ++qq) {
        int lr = qq * 8 + q;
        int m  = row0 + lr;
        int b  = m >> 12, pix = m & 4095;
        int rbatch = (b * 8 + h) & 15;  // faithful: tile() => ref batch = (b*H+h) % B
        const float* rp = ref_point + ((size_t)rbatch * 4096 + pix) * 2;
        float rx = rp[0] * 63.0f;
        float ry = rp[1] * 63.0f;
        const bf16* kfh = kf + ((size_t)(b * 8 + h) * 4096) * 32 + cg * 8;
        float acc[8] = {};
#pragma unroll
        for (int k = 0; k < 4; ++k) {
            const float* op = off_ws + (size_t)m * 64 + (h * 4 + k) * 2;
            float ox = op[0], oy = op[1];
            float a  = A_ws[(size_t)m * 32 + h * 4 + k];
            float px = (rx + ox) * (64.0f / 63.0f) - 0.5f;   // align_corners=False unnormalize
            float py = (ry + oy) * (64.0f / 63.0f) - 0.5f;
            float x0 = floorf(px), y0 = floorf(py);
            float wx1 = px - x0, wy1 = py - y0;
            int xi = (int)x0, yi = (int)y0;
            float ax0 = (1.f - wx1) * ((xi     >= 0 && xi     < 64) ? 1.f : 0.f);
            float ax1 = wx1         * ((xi + 1 >= 0 && xi + 1 < 64) ? 1.f : 0.f);
            float ay0 = (1.f - wy1) * ((yi     >= 0 && yi     < 64) ? a : 0.f);
            float ay1 = wy1         * ((yi + 1 >= 0 && yi + 1 < 64) ? a : 0.f);
            int xc0 = min(max(xi, 0), 63),      xc1 = min(max(xi + 1, 0), 63);
            int yc0 = min(max(yi, 0), 63) * 64, yc1 = min(max(yi + 1, 0), 63) * 64;
            bf16x8 v00 = *(const bf16x8*)(kfh + (yc0 + xc0) * 32);
            bf16x8 v01 = *(const bf16x8*)(kfh + (yc0 + xc1) * 32);
            bf16x8 v10 = *(const bf16x8*)(kfh + (yc1 + xc0) * 32);
            bf16x8 v11 = *(const bf16x8*)(kfh + (yc1 + xc1) * 32);
            float w00 = ax0 * ay0, w01 = ax1 * ay0, w10 = ax0 * ay1, w11 = ax1 * ay1;
#pragma unroll
            for (int e = 0; e < 8; ++e) {
                acc[e] += w00 * bs2f(v00[e]) + w01 * bs2f(v01[e])
                        + w10 * bs2f(v10[e]) + w11 * bs2f(v11[e]);
            }
        }
        bf16x8 o;
#pragma unroll
        for (int e = 0; e < 8; ++e) o[e] = f2bs(acc[e]);
        *(bf16x8*)(As + lr * 512 + ((gcol ^ (lr & 7)) << 4)) = o;
    }
    __syncthreads();

    // phase G: out GEMM, A from LDS tile, B single-buffered 32KB slices
    f32x4 acc2[2][8] = {};
    int lane = tid & 63, wave = tid >> 6;
    const int rsub = lane & 15, kg = lane >> 4;
    const int rg = wave >> 1, cgw = wave & 1;
#pragma unroll
    for (int s = 0; s < 4; ++s) {
#pragma unroll
        for (int i = 0; i < 8; ++i) {      // stage B slice s (8 gll per wave)
            int i16 = (wave * 8 + i) * 64 + lane;
            int n = i16 >> 3, lg = i16 & 7;
            gll16(WmT + (size_t)n * 256 + s * 64 + lg * 8, (char*)Bs + (size_t)i16 * 16);
        }
        asm volatile("s_waitcnt vmcnt(0)" ::: "memory");
        __builtin_amdgcn_s_barrier();
#pragma unroll
        for (int kkl = 0; kkl < 2; ++kkl) {
            bf16x8 afr[2];
#pragma unroll
            for (int st = 0; st < 2; ++st) {
                int lr = rg * 32 + st * 16 + rsub;
                int g = s * 8 + kkl * 4 + kg;
                afr[st] = *(const bf16x8*)(As + lr * 512 + ((g ^ (lr & 7)) << 4));
            }
            int lg = kkl * 4 + kg;
#pragma unroll
            for (int nt = 0; nt < 8; ++nt) {
                int n = cgw * 128 + nt * 16 + rsub;
                bf16x8 b = *(const bf16x8*)((const char*)Bs + (size_t)n * 128 + ((lg ^ (n & 7)) << 4));
                acc2[0][nt] = __builtin_amdgcn_mfma_f32_16x16x32_bf16(afr[0], b, acc2[0][nt], 0, 0, 0);
                acc2[1][nt] = __builtin_amdgcn_mfma_f32_16x16x32_bf16(afr[1], b, acc2[1][nt], 0, 0, 0);
            }
        }
        asm volatile("s_waitcnt lgkmcnt(0)" ::: "memory");
        __builtin_amdgcn_s_barrier();
    }
    // epilogue
    int col = lane & 15;
    int jbase = cgw * 128;
    int rb = row0 + rg * 32 + ((lane >> 4) << 2);
#pragma unroll
    for (int mt = 0; mt < 2; ++mt)
#pragma unroll
        for (int nt = 0; nt < 8; ++nt) {
            int j = jbase + nt * 16 + col;
            float bias = bm[j];
#pragma unroll
            for (int r = 0; r < 4; ++r)
                out[(size_t)(rb + mt * 16 + r) * DD + j] =
                    acc2[mt][nt][r] + bias;
        }
}

extern "C" void kernel_launch(void* const* d_in, const int* in_sizes, int n_in,
                              void* d_out, int out_size, void* d_ws, size_t ws_size,
                              hipStream_t stream)
{
    (void)in_sizes; (void)n_in; (void)out_size; (void)ws_size;
    // setup_inputs order (all float32):
    // 0 query (unused) 1 keys 2 ref_point 3 src_query 4 Wq 5 bq 6 Wb 7 bb
    // 8 Wk 9 bk 10 Woff 11 boff 12 WA 13 bA 14 Wm 15 bm
    const float* keys = (const float*)d_in[1];
    const float* refp = (const float*)d_in[2];
    const float* srcq = (const float*)d_in[3];
    const float* Wb   = (const float*)d_in[6];
    const float* bb   = (const float*)d_in[7];
    const float* Wk   = (const float*)d_in[8];
    const float* bk   = (const float*)d_in[9];
    const float* Woff = (const float*)d_in[10];
    const float* boff = (const float*)d_in[11];
    const float* WA   = (const float*)d_in[12];
    const float* bA   = (const float*)d_in[13];
    const float* Wm   = (const float*)d_in[14];
    const float* bm   = (const float*)d_in[15];

    char* ws = (char*)d_ws;
    bf16*  WbT    = (bf16*)(ws + 0);                    // 128 KiB (swizzled)
    bf16*  WkT    = (bf16*)(ws + 131072);               // 128 KiB (swizzled)
    bf16*  WmT    = (bf16*)(ws + 262144);               // 128 KiB (swizzled)
    bf16*  WoffAT = (bf16*)(ws + 393216);               // 48 KiB  [96][256] (swizzled)
    bf16*  kf_ws  = (bf16*)(ws + 442368 + 33554432ull);             // 32 MiB
    float* off_ws = (float*)(ws + 442368 + 3ull * 33554432ull);     // 16 MiB  [65536][64]
    float* A_ws   = (float*)(ws + 442368 + 3ull * 33554432ull + 16777216ull); // 8 MiB [65536][32]

    float* out = (float*)d_out;

    k_transpose <<<864, 256, 0, stream>>>(Wb, Wk, Wm, Woff, WA, WbT, WkT, WmT, WoffAT);
    k_fusedA    <<<2048, 256, 0, stream>>>(srcq, WbT, bb, WoffAT, boff, bA, off_ws, A_ws,
                                           keys, WkT, bk, kf_ws);
    k_sample_out<<<1024, 256, 0, stream>>>(refp, off_ws, A_ws, kf_ws, WmT, bm, out);
}

// Round 10
// 121.745 us; speedup vs baseline: 1.0623x; 1.0623x over previous
//
#include <hip/hip_runtime.h>
#include <hip/hip_bf16.h>

using bf16 = __hip_bfloat16;
typedef short bf16x8 __attribute__((ext_vector_type(8)));
typedef float f32x4 __attribute__((ext_vector_type(4)));

#define DD 256
#define MTOT 65536   // B*QH*QW = 16*64*64

static __device__ __forceinline__ short f2bs(float f) {
    bf16 h = __float2bfloat16(f);          // RNE
    return *reinterpret_cast<short*>(&h);
}
static __device__ __forceinline__ float bs2f(short s) {
    unsigned u = (unsigned)(unsigned short)s << 16;
    return __uint_as_float(u);
}

// async global->LDS, 16B per lane; LDS dest = wave-uniform base + lane*16
static __device__ __forceinline__ void gll16(const void* g, void* l) {
    __builtin_amdgcn_global_load_lds(
        (const __attribute__((address_space(1))) unsigned int*)g,
        (__attribute__((address_space(3))) unsigned int*)l, 16, 0, 0);
}

// Pre-swizzled BT layout in GLOBAL: element (n = out col, k) at flat
//   n*256 + (((k>>3) ^ (n&7)) << 3 | (k&7))
// 16B-granule XOR closed within each 64-k slice -> LDS staging is a linear
// copy, ds_read at [n][lg ^ (n&7)] bank-optimal (R5/R7: 0 conflicts).
static __device__ __forceinline__ int swz_idx(int n, int k) {
    return n * 256 + ((((k >> 3) ^ (n & 7)) << 3) | (k & 7));
}

// ---------------- K0: convert+transpose+swizzle weights (f32 -> bf16) ----------------
__global__ __launch_bounds__(256) void k_transpose(
    const float* __restrict__ Wb, const float* __restrict__ Wk, const float* __restrict__ Wm,
    const float* __restrict__ Woff, const float* __restrict__ WA,
    bf16* __restrict__ WbT, bf16* __restrict__ WkT, bf16* __restrict__ WmT,
    bf16* __restrict__ WoffAT)
{
    int idx = blockIdx.x * 256 + threadIdx.x;
    if (idx < 3 * 65536) {
        int which = idx >> 16, e = idx & 65535;
        int i = e >> 8, j = e & 255;               // in[i][j]: i = k, j = n
        const float* src = which == 0 ? Wb : (which == 1 ? Wk : Wm);
        bf16*        dst = which == 0 ? WbT : (which == 1 ? WkT : WmT);
        dst[swz_idx(j, i)] = __float2bfloat16(src[e]);
    } else {
        int e = idx - 3 * 65536;
        if (e < 96 * 256) {
            int j = e >> 8, i = e & 255;           // out row j = n (0..95), k = i
            WoffAT[swz_idx(j, i)] = __float2bfloat16((j < 64) ? Woff[i * 64 + j]
                                                              : WA[i * 32 + (j - 64)]);
        }
    }
}

// ---------------- double-buffered global_load_lds MFMA mainloop (R7, unchanged) ----------------
template <int NTW, int NCOLS, bool AF32>
static __device__ __forceinline__ void gemm_lds2(
    const void* __restrict__ Av, const bf16* __restrict__ BTswz,
    bf16* __restrict__ Bs, char* __restrict__ As,
    int row0, int tid, f32x4 (&acc)[2][NTW])
{
    const int wave = tid >> 6, lane = tid & 63;
    const int rg = wave >> 1, cg = wave & 1;
    const int rsub = lane & 15, kg = lane >> 4;
    constexpr int SB = NCOLS / 32;
    constexpr int SA = AF32 ? 4 : 2;
    constexpr int ABYTES = AF32 ? 16384 : 8192;

    auto stageB = [&](int s) {
#pragma unroll
        for (int i = 0; i < SB; ++i) {
            int cc = wave * SB + i;
            int i16 = cc * 64 + lane;
            int n = i16 >> 3, lg = i16 & 7;
            gll16(BTswz + (size_t)n * 256 + s * 64 + lg * 8, (char*)Bs + (size_t)i16 * 16);
        }
    };
    auto stageA = [&](int s, int buf) {
#pragma unroll
        for (int i = 0; i < SA; ++i) {
            if constexpr (AF32) {
                int cc = wave * 4 + i;
                int row = cc * 4 + (lane >> 4);
                int g = (lane & 15) ^ (row & 15);
                gll16((const float*)Av + (size_t)(row0 + row) * DD + s * 64 + g * 4,
                      As + (size_t)buf * ABYTES + cc * 1024 + lane * 16);
            } else {
                int cc = wave * 2 + i;
                int row = cc * 8 + (lane >> 3);
                int g = (lane & 7) ^ (row & 7);
                gll16((const bf16*)Av + (size_t)(row0 + row) * DD + s * 64 + g * 8,
                      As + (size_t)buf * ABYTES + cc * 1024 + lane * 16);
            }
        }
    };

    stageA(0, 0);
    int cur = 0;
#pragma unroll
    for (int s = 0; s < 4; ++s) {
        stageB(s);
        if (s < 3) {
            stageA(s + 1, cur ^ 1);
            asm volatile("s_waitcnt vmcnt(%0)" :: "i"(SA) : "memory");
        } else {
            asm volatile("s_waitcnt vmcnt(0)" ::: "memory");
        }
        __builtin_amdgcn_s_barrier();
#pragma unroll
        for (int kkl = 0; kkl < 2; ++kkl) {
            bf16x8 afr[2];
#pragma unroll
            for (int st = 0; st < 2; ++st) {
                int row = rg * 32 + st * 16 + rsub;
                if constexpr (AF32) {
                    const char* base = As + cur * ABYTES + row * 256;
                    int G0 = kkl * 8 + kg * 2;
                    f32x4 v0 = *(const f32x4*)(base + ((G0 ^ (row & 15)) << 4));
                    f32x4 v1 = *(const f32x4*)(base + (((G0 + 1) ^ (row & 15)) << 4));
                    bf16x8 a;
#pragma unroll
                    for (int e = 0; e < 4; ++e) { a[e] = f2bs(v0[e]); a[e + 4] = f2bs(v1[e]); }
                    afr[st] = a;
                } else {
                    const char* base = As + cur * ABYTES + row * 128;
                    int g = kkl * 4 + kg;
                    afr[st] = *(const bf16x8*)(base + ((g ^ (row & 7)) << 4));
                }
            }
            int lg = kkl * 4 + kg;
#pragma unroll
            for (int nt = 0; nt < NTW; ++nt) {
                int n = cg * (NTW * 16) + nt * 16 + rsub;
                bf16x8 b = *(const bf16x8*)((const char*)Bs + (size_t)n * 128 + ((lg ^ (n & 7)) << 4));
                acc[0][nt] = __builtin_amdgcn_mfma_f32_16x16x32_bf16(afr[0], b, acc[0][nt], 0, 0, 0);
                acc[1][nt] = __builtin_amdgcn_mfma_f32_16x16x32_bf16(afr[1], b, acc[1][nt], 0, 0, 0);
            }
        }
        asm volatile("s_waitcnt lgkmcnt(0)" ::: "memory");
        __builtin_amdgcn_s_barrier();
        cur ^= 1;
    }
}

// ---------------- body: fused sq + offA (LDS passed in) ----------------
static __device__ void body_sqoffA(
    int bid, char* smem,
    const float* __restrict__ src, const bf16* __restrict__ WbT, const float* __restrict__ bb,
    const bf16* __restrict__ WoffAT, const float* __restrict__ boff, const float* __restrict__ bA,
    float* __restrict__ off_ws, float* __restrict__ A_ws)
{
    bf16* Bs = (bf16*)smem;            // 32 KB
    char* As = smem + 32768;           // 32 KB
    int tid = threadIdx.x, lane = tid & 63, wave = tid >> 6;
    int row0 = bid * 64;
    f32x4 acc[2][8] = {};
    gemm_lds2<8, 256, true>(src, WbT, Bs, As, row0, tid, acc);

    // phase 2: write sq tile (bias + bf16) into As, swizzled
    {
        int col = lane & 15;
        int jbase = (wave & 1) * 128;
        int lrb = (wave >> 1) * 32 + ((lane >> 4) << 2);
#pragma unroll
        for (int mt = 0; mt < 2; ++mt)
#pragma unroll
            for (int nt = 0; nt < 8; ++nt) {
                int j = jbase + nt * 16 + col;
                float bias = bb[j];
                int g = j >> 3;
#pragma unroll
                for (int r = 0; r < 4; ++r) {
                    int lr = lrb + mt * 16 + r;
                    *(short*)(As + lr * 512 + (((g ^ (lr & 7)) << 4)) + (j & 7) * 2) =
                        f2bs(acc[mt][nt][r] + bias);
                }
            }
    }
    __syncthreads();

    // phase 3: offA mainloop; A full-K resident in As, B sliced (12 KB) dbuf in Bs
    f32x4 acc2[2][3] = {};
    const int rsub = lane & 15, kg = lane >> 4;
    const int rg = wave >> 1, cg2 = wave & 1;
    auto stageOB = [&](int s, int buf) {
#pragma unroll
        for (int i = 0; i < 3; ++i) {
            int i16 = (wave * 3 + i) * 64 + lane;      // 0..767 granules
            int n = i16 >> 3, lg = i16 & 7;
            gll16(WoffAT + (size_t)n * 256 + s * 64 + lg * 8,
                  (char*)Bs + buf * 12288 + (size_t)i16 * 16);
        }
    };
    stageOB(0, 0);
    int cur = 0;
#pragma unroll
    for (int s = 0; s < 4; ++s) {
        if (s < 3) {
            stageOB(s + 1, cur ^ 1);
            asm volatile("s_waitcnt vmcnt(3)" ::: "memory");   // slice s done; s+1 in flight
        } else {
            asm volatile("s_waitcnt vmcnt(0)" ::: "memory");
        }
        __builtin_amdgcn_s_barrier();
#pragma unroll
        for (int kkl = 0; kkl < 2; ++kkl) {
            bf16x8 afr[2];
#pragma unroll
            for (int st = 0; st < 2; ++st) {
                int lr = rg * 32 + st * 16 + rsub;
                int g = s * 8 + kkl * 4 + kg;
                afr[st] = *(const bf16x8*)(As + lr * 512 + ((g ^ (lr & 7)) << 4));
            }
            int lg = kkl * 4 + kg;
#pragma unroll
            for (int nt = 0; nt < 3; ++nt) {
                int n = cg2 * 48 + nt * 16 + rsub;
                bf16x8 b = *(const bf16x8*)((const char*)Bs + cur * 12288 + (size_t)n * 128
                                            + ((lg ^ (n & 7)) << 4));
                acc2[0][nt] = __builtin_amdgcn_mfma_f32_16x16x32_bf16(afr[0], b, acc2[0][nt], 0, 0, 0);
                acc2[1][nt] = __builtin_amdgcn_mfma_f32_16x16x32_bf16(afr[1], b, acc2[1][nt], 0, 0, 0);
            }
        }
        asm volatile("s_waitcnt lgkmcnt(0)" ::: "memory");
        __builtin_amdgcn_s_barrier();
        cur ^= 1;
    }
    // epilogue: off + softmax(A)
    int col = lane & 15;
    int jbase = cg2 * 48;
    int rb = row0 + rg * 32 + ((lane >> 4) << 2);
#pragma unroll
    for (int mt = 0; mt < 2; ++mt) {
#pragma unroll
        for (int nt = 0; nt < 3; ++nt) {
            int j = jbase + nt * 16 + col;          // 0..95
            if (j < 64) {                           // offsets
                float bias = boff[j];
#pragma unroll
                for (int r = 0; r < 4; ++r) {
                    int m = rb + mt * 16 + r;
                    off_ws[(size_t)m * 64 + j] = acc2[mt][nt][r] + bias;
                }
            } else {                                // A logits, ac = j-64 in 0..31
                int ac = j - 64;                    // head = ac>>2, slot = ac&3
                float bias = bA[ac];
#pragma unroll
                for (int r = 0; r < 4; ++r) {
                    int m = rb + mt * 16 + r;
                    float v  = acc2[mt][nt][r] + bias;
                    float mx = fmaxf(v, __shfl_xor(v, 1));
                    mx       = fmaxf(mx, __shfl_xor(mx, 2));
                    float e  = __expf(v - mx);
                    float su = e + __shfl_xor(e, 1);
                    su      += __shfl_xor(su, 2);
                    A_ws[(size_t)m * 32 + ac] = e / su;
                }
            }
        }
    }
}

// ---------------- body: kf = keys @ Wk + bk (LDS passed in) ----------------
static __device__ void body_kf(
    int bid, char* smem,
    const float* __restrict__ keys, const bf16* __restrict__ WkT,
    const float* __restrict__ bk, bf16* __restrict__ kf)
{
    bf16* Bs = (bf16*)smem;            // 32 KB
    char* As = smem + 32768;           // 32 KB (f32 dbuf)
    int tid = threadIdx.x, lane = tid & 63, wave = tid >> 6;
    int row0 = bid * 64;
    f32x4 acc[2][8] = {};
    gemm_lds2<8, 256, true>(keys, WkT, Bs, As, row0, tid, acc);
    int col = lane & 15;
    int jbase = (wave & 1) * 128;
    int rb = row0 + (wave >> 1) * 32 + ((lane >> 4) << 2);
#pragma unroll
    for (int mt = 0; mt < 2; ++mt)
#pragma unroll
        for (int nt = 0; nt < 8; ++nt) {
            int j = jbase + nt * 16 + col;         // head h=j>>5, channel c=j&31
            float bias = bk[j];
#pragma unroll
            for (int r = 0; r < 4; ++r) {
                int m = rb + mt * 16 + r;          // b = m>>12, pix = m&4095
                size_t dst = (((size_t)(m >> 12) * 8 + (j >> 5)) * 4096 + (m & 4095)) * 32 + (j & 31);
                kf[dst] = __float2bfloat16(acc[mt][nt][r] + bias);
            }
        }
}

// ---------------- K1: role-split fused kernel: even blocks sqoffA, odd blocks kf ----------------
__global__ __launch_bounds__(256) void k_fusedA(
    const float* __restrict__ src, const bf16* __restrict__ WbT, const float* __restrict__ bb,
    const bf16* __restrict__ WoffAT, const float* __restrict__ boff, const float* __restrict__ bA,
    float* __restrict__ off_ws, float* __restrict__ A_ws,
    const float* __restrict__ keys, const bf16* __restrict__ WkT,
    const float* __restrict__ bk, bf16* __restrict__ kf)
{
    __shared__ __align__(16) char smem[65536];
    int bid = blockIdx.x;
    if (bid & 1)
        body_kf(bid >> 1, smem, keys, WkT, bk, kf);
    else
        body_sqoffA(bid >> 1, smem, src, WbT, bb, WoffAT, boff, bA, off_ws, A_ws);
}

// ---------------- K2: bilinear gather, XCD-partitioned by batch (R8) ----------------
// bid&7 = XCD slot owning 2 batches -> kf working set per L2 = 2 MB.
// off/A first-level loads vectorized: 32B + 16B contiguous per (m,h).
__global__ __launch_bounds__(256) void k_sample(
    const float* __restrict__ ref_point, const float* __restrict__ off_ws,
    const float* __restrict__ A_ws, const bf16* __restrict__ kf,
    bf16* __restrict__ feat)
{
    int bid = blockIdx.x;
    int xcd = bid & 7, within = bid >> 3;
    int bb_ = xcd * 2 + (within >> 9);   // batch 0..15
    int pixblk = within & 511;
    int t  = threadIdx.x;
    int q  = t >> 5;             // 0..7
    int h  = (t >> 2) & 7;       // 0..7
    int cg = t & 3;              // 0..3 -> channels cg*8..cg*8+7
    int m  = (bb_ << 12) + pixblk * 8 + q;
    int b  = bb_, pix = m & 4095;
    int rbatch = (b * 8 + h) & 15;      // faithful: tile() => ref batch = (b*H+h) % B
    const float* rp = ref_point + ((size_t)rbatch * 4096 + pix) * 2;
    float rx = rp[0] * 63.0f;
    float ry = rp[1] * 63.0f;
    const bf16* kfh = kf + ((size_t)(b * 8 + h) * 4096) * 32 + cg * 8;
    // vectorized first-level loads: off pairs for k=0..3 are 8 consecutive f32
    f32x4 o0 = *(const f32x4*)(off_ws + (size_t)m * 64 + h * 8);
    f32x4 o1 = *(const f32x4*)(off_ws + (size_t)m * 64 + h * 8 + 4);
    f32x4 av = *(const f32x4*)(A_ws  + (size_t)m * 32 + h * 4);
    float acc[8] = {};
#pragma unroll
    for (int k = 0; k < 4; ++k) {
        float ox = (k < 2) ? o0[2 * k] : o1[2 * k - 4];
        float oy = (k < 2) ? o0[2 * k + 1] : o1[2 * k - 3];
        float a  = av[k];
        float px = (rx + ox) * (64.0f / 63.0f) - 0.5f;   // align_corners=False unnormalize
        float py = (ry + oy) * (64.0f / 63.0f) - 0.5f;
        float x0 = floorf(px), y0 = floorf(py);
        float wx1 = px - x0, wy1 = py - y0;
        int xi = (int)x0, yi = (int)y0;
        float ax0 = (1.f - wx1) * ((xi     >= 0 && xi     < 64) ? 1.f : 0.f);
        float ax1 = wx1         * ((xi + 1 >= 0 && xi + 1 < 64) ? 1.f : 0.f);
        float ay0 = (1.f - wy1) * ((yi     >= 0 && yi     < 64) ? a : 0.f);
        float ay1 = wy1         * ((yi + 1 >= 0 && yi + 1 < 64) ? a : 0.f);
        int xc0 = min(max(xi, 0), 63),      xc1 = min(max(xi + 1, 0), 63);
        int yc0 = min(max(yi, 0), 63) * 64, yc1 = min(max(yi + 1, 0), 63) * 64;
        bf16x8 v00 = *(const bf16x8*)(kfh + (yc0 + xc0) * 32);
        bf16x8 v01 = *(const bf16x8*)(kfh + (yc0 + xc1) * 32);
        bf16x8 v10 = *(const bf16x8*)(kfh + (yc1 + xc0) * 32);
        bf16x8 v11 = *(const bf16x8*)(kfh + (yc1 + xc1) * 32);
        float w00 = ax0 * ay0, w01 = ax1 * ay0, w10 = ax0 * ay1, w11 = ax1 * ay1;
#pragma unroll
        for (int e = 0; e < 8; ++e) {
            acc[e] += w00 * bs2f(v00[e]) + w01 * bs2f(v01[e])
                    + w10 * bs2f(v10[e]) + w11 * bs2f(v11[e]);
        }
    }
    bf16x8 o;
#pragma unroll
    for (int e = 0; e < 8; ++e) o[e] = f2bs(acc[e]);
    *(bf16x8*)(feat + (size_t)m * DD + h * 32 + cg * 8) = o;
}

// ---------------- K3: out = feat @ Wm + bm -> f32 (R7) ----------------
__global__ __launch_bounds__(256) void k_gemm_out(
    const bf16* __restrict__ feat, const bf16* __restrict__ WmT,
    const float* __restrict__ bm, float* __restrict__ out)
{
    __shared__ __align__(16) bf16 Bs[256 * 64];
    __shared__ __align__(16) char As[2 * 8192];
    int tid = threadIdx.x, lane = tid & 63, wave = tid >> 6;
    int row0 = blockIdx.x * 64;
    f32x4 acc[2][8] = {};
    gemm_lds2<8, 256, false>(feat, WmT, Bs, As, row0, tid, acc);
    int col = lane & 15;
    int jbase = (wave & 1) * 128;
    int rb = row0 + (wave >> 1) * 32 + ((lane >> 4) << 2);
#pragma unroll
    for (int mt = 0; mt < 2; ++mt)
#pragma unroll
        for (int nt = 0; nt < 8; ++nt) {
            int j = jbase + nt * 16 + col;
            float bias = bm[j];
#pragma unroll
            for (int r = 0; r < 4; ++r)
                out[(size_t)(rb + mt * 16 + r) * DD + j] =
                    acc[mt][nt][r] + bias;
        }
}

extern "C" void kernel_launch(void* const* d_in, const int* in_sizes, int n_in,
                              void* d_out, int out_size, void* d_ws, size_t ws_size,
                              hipStream_t stream)
{
    (void)in_sizes; (void)n_in; (void)out_size; (void)ws_size;
    // setup_inputs order (all float32):
    // 0 query (unused) 1 keys 2 ref_point 3 src_query 4 Wq 5 bq 6 Wb 7 bb
    // 8 Wk 9 bk 10 Woff 11 boff 12 WA 13 bA 14 Wm 15 bm
    const float* keys = (const float*)d_in[1];
    const float* refp = (const float*)d_in[2];
    const float* srcq = (const float*)d_in[3];
    const float* Wb   = (const float*)d_in[6];
    const float* bb   = (const float*)d_in[7];
    const float* Wk   = (const float*)d_in[8];
    const float* bk   = (const float*)d_in[9];
    const float* Woff = (const float*)d_in[10];
    const float* boff = (const float*)d_in[11];
    const float* WA   = (const float*)d_in[12];
    const float* bA   = (const float*)d_in[13];
    const float* Wm   = (const float*)d_in[14];
    const float* bm   = (const float*)d_in[15];

    char* ws = (char*)d_ws;
    bf16*  WbT    = (bf16*)(ws + 0);                    // 128 KiB (swizzled)
    bf16*  WkT    = (bf16*)(ws + 131072);               // 128 KiB (swizzled)
    bf16*  WmT    = (bf16*)(ws + 262144);               // 128 KiB (swizzled)
    bf16*  WoffAT = (bf16*)(ws + 393216);               // 48 KiB  [96][256] (swizzled)
    bf16*  kf_ws  = (bf16*)(ws + 442368 + 33554432ull);             // 32 MiB
    bf16*  feat_ws= (bf16*)(ws + 442368 + 2ull * 33554432ull);      // 32 MiB
    float* off_ws = (float*)(ws + 442368 + 3ull * 33554432ull);     // 16 MiB  [65536][64]
    float* A_ws   = (float*)(ws + 442368 + 3ull * 33554432ull + 16777216ull); // 8 MiB [65536][32]

    float* out = (float*)d_out;

    k_transpose<<<864, 256, 0, stream>>>(Wb, Wk, Wm, Woff, WA, WbT, WkT, WmT, WoffAT);
    k_fusedA   <<<2048, 256, 0, stream>>>(srcq, WbT, bb, WoffAT, boff, bA, off_ws, A_ws,
                                          keys, WkT, bk, kf_ws);
    k_sample   <<<8192, 256, 0, stream>>>(refp, off_ws, A_ws, kf_ws, feat_ws);
    k_gemm_out <<<1024, 256, 0, stream>>>(feat_ws, WmT, bm, out);
}